// Round 5
// baseline (534.991 us; speedup 1.0000x reference)
//
#include <hip/hip_runtime.h>

// ArDCA loss: loss = -sum_{m,i} W[m] * log_softmax(h[i,:] + sum_{j<i} J[i,j,:,X[m,j]])[X[m,i]]
//             + 1e-6 * sum h^2 + 1e-4 * sum_{j<i} J^2
// M=8192, L=256, Q=21. Output: single fp32 scalar.
//
// R5: fp8(e4m3) LDS tiles, f32 accumulation. Row (jc,b) = 21 fp8 split as
// JA[row]=float4 (16 fp8, stride 16 B -> <=3-way bank groups) +
// JB[row]=float2 (5 fp8 + pad, stride 8 B -> <=2-way = free). Gather is
// ds_read_b128 + ds_read_b64 (24 B/item vs R4's 48 B). Unpack with
// v_cvt_pk_f32_fp8 (11/item) + 21 v_add_f32 -> modeled ~125 us VALU-busy,
// under the ~165 us LDS path.
// J ~ N(0,1e-4) lives in e4m3's subnormal range -> pre-scale by 64 at pack
// (sigma -> 0.64, normal range), unscale x(1/64) in the epilogue.
// Reg terms (sum J^2 lower-tri, sum h^2) folded into blockIdx.x==0 staging
// on the exact fp32 values (R4).
// Note: dur_us carries a ~110 us harness constant (input restore) on top of
// the pair dispatch.

#define M_SEQ 8192
#define L_POS 256
#define Q_SYM 21
#define QQ    441
#define JC    16
#define NROWS (JC * Q_SYM)       // 336 rows per chunk

typedef float f32x2 __attribute__((ext_vector_type(2)));

__device__ __forceinline__ unsigned pack4_fp8(float a, float b, float c, float d) {
    int w = __builtin_amdgcn_cvt_pk_fp8_f32(a, b, 0, false);   // bytes 0,1
    w = __builtin_amdgcn_cvt_pk_fp8_f32(c, d, w, true);        // bytes 2,3
    return (unsigned)w;
}

__device__ __forceinline__ float wave_block_reduce(float v, float* red, int tid) {
    #pragma unroll
    for (int off = 32; off > 0; off >>= 1) v += __shfl_down(v, off, 64);
    if ((tid & 63) == 0) red[tid >> 6] = v;
    __syncthreads();
    return red[0] + red[1] + red[2] + red[3];
}

__global__ void zero_out(float* __restrict__ out) { out[0] = 0.0f; }

// One block per (m-chunk of 256, i). Each thread owns one m.
__global__ __launch_bounds__(256) void pair_nll_kernel(const int* __restrict__ X,
                                                       const float* __restrict__ W,
                                                       const float* __restrict__ h,
                                                       const float* __restrict__ J,
                                                       float* __restrict__ out) {
    __shared__ float4 JA[NROWS];     // 16 fp8 per row  (values 0..15)  5376 B
    __shared__ float2 JB[NROWS];     // 5 fp8 + pad     (values 16..20) 2688 B
    __shared__ float red[4];

    const int tid = threadIdx.x;
    const int i  = blockIdx.y;
    const int m  = blockIdx.x * 256 + tid;
    const bool do_reg = (blockIdx.x == 0);
    const int* xrow = X + (size_t)m * L_POS;

    // thread-owned staging rows (fixed for whole kernel)
    const int row0 = tid;                       // 0..255
    const int jc0  = row0 / Q_SYM;
    const int b0   = row0 - jc0 * Q_SYM;
    const int row1 = tid + 256;                 // 256..335 valid when tid < 80
    const int jc1  = row1 / Q_SYM;
    const int b1   = row1 - jc1 * Q_SYM;
    const bool has_row1 = (row1 < NROWS);

    float acc[Q_SYM];
    #pragma unroll
    for (int a = 0; a < Q_SYM; ++a) acc[a] = 0.0f;
    float regsum = 0.0f;
    const float SC = 64.0f;

    for (int j0 = 0; j0 < i; j0 += JC) {
        const float* Jsrc = J + ((size_t)i * L_POS + j0) * QQ;
        __syncthreads();   // protect previous chunk's LDS reads

        // ---- stage: each thread converts+packs its row(s)
        {
            const float* s = Jsrc + jc0 * QQ + b0;
            float v[Q_SYM];
            #pragma unroll
            for (int a = 0; a < Q_SYM; ++a) v[a] = s[a * Q_SYM];
            if (do_reg && (j0 + jc0 < i)) {
                float rs = 0.0f;
                #pragma unroll
                for (int a = 0; a < Q_SYM; ++a) rs += v[a] * v[a];
                regsum += rs;
            }
            unsigned w0 = pack4_fp8(SC*v[0],  SC*v[1],  SC*v[2],  SC*v[3]);
            unsigned w1 = pack4_fp8(SC*v[4],  SC*v[5],  SC*v[6],  SC*v[7]);
            unsigned w2 = pack4_fp8(SC*v[8],  SC*v[9],  SC*v[10], SC*v[11]);
            unsigned w3 = pack4_fp8(SC*v[12], SC*v[13], SC*v[14], SC*v[15]);
            unsigned w4 = pack4_fp8(SC*v[16], SC*v[17], SC*v[18], SC*v[19]);
            unsigned w5 = (unsigned)__builtin_amdgcn_cvt_pk_fp8_f32(SC*v[20], 0.f, 0, false);
            JA[row0] = make_float4(__builtin_bit_cast(float, w0),
                                   __builtin_bit_cast(float, w1),
                                   __builtin_bit_cast(float, w2),
                                   __builtin_bit_cast(float, w3));
            JB[row0] = make_float2(__builtin_bit_cast(float, w4),
                                   __builtin_bit_cast(float, w5));
        }
        if (has_row1) {
            const float* s = Jsrc + jc1 * QQ + b1;
            float v[Q_SYM];
            #pragma unroll
            for (int a = 0; a < Q_SYM; ++a) v[a] = s[a * Q_SYM];
            if (do_reg && (j0 + jc1 < i)) {
                float rs = 0.0f;
                #pragma unroll
                for (int a = 0; a < Q_SYM; ++a) rs += v[a] * v[a];
                regsum += rs;
            }
            unsigned w0 = pack4_fp8(SC*v[0],  SC*v[1],  SC*v[2],  SC*v[3]);
            unsigned w1 = pack4_fp8(SC*v[4],  SC*v[5],  SC*v[6],  SC*v[7]);
            unsigned w2 = pack4_fp8(SC*v[8],  SC*v[9],  SC*v[10], SC*v[11]);
            unsigned w3 = pack4_fp8(SC*v[12], SC*v[13], SC*v[14], SC*v[15]);
            unsigned w4 = pack4_fp8(SC*v[16], SC*v[17], SC*v[18], SC*v[19]);
            unsigned w5 = (unsigned)__builtin_amdgcn_cvt_pk_fp8_f32(SC*v[20], 0.f, 0, false);
            JA[row1] = make_float4(__builtin_bit_cast(float, w0),
                                   __builtin_bit_cast(float, w1),
                                   __builtin_bit_cast(float, w2),
                                   __builtin_bit_cast(float, w3));
            JB[row1] = make_float2(__builtin_bit_cast(float, w4),
                                   __builtin_bit_cast(float, w5));
        }
        __syncthreads();

        // ---- this thread's 16 X values (row-contiguous, vectorized)
        int4 xa = *(const int4*)(xrow + j0);
        int4 xb = *(const int4*)(xrow + j0 + 4);
        int4 xc = *(const int4*)(xrow + j0 + 8);
        int4 xd = *(const int4*)(xrow + j0 + 12);
        int xv[JC] = {xa.x, xa.y, xa.z, xa.w, xb.x, xb.y, xb.z, xb.w,
                      xc.x, xc.y, xc.z, xc.w, xd.x, xd.y, xd.z, xd.w};

        #pragma unroll
        for (int jc = 0; jc < JC; ++jc) {
            if (j0 + jc < i) {   // block-uniform guard (scalar branch)
                int r = jc * Q_SYM + xv[jc];
                float4 lo = JA[r];
                float2 hi = JB[r];
                unsigned d0 = __builtin_bit_cast(unsigned, lo.x);
                unsigned d1 = __builtin_bit_cast(unsigned, lo.y);
                unsigned d2 = __builtin_bit_cast(unsigned, lo.z);
                unsigned d3 = __builtin_bit_cast(unsigned, lo.w);
                unsigned d4 = __builtin_bit_cast(unsigned, hi.x);
                unsigned d5 = __builtin_bit_cast(unsigned, hi.y);
                f32x2 p;
                p = __builtin_amdgcn_cvt_pk_f32_fp8(d0, false); acc[0]  += p.x; acc[1]  += p.y;
                p = __builtin_amdgcn_cvt_pk_f32_fp8(d0, true);  acc[2]  += p.x; acc[3]  += p.y;
                p = __builtin_amdgcn_cvt_pk_f32_fp8(d1, false); acc[4]  += p.x; acc[5]  += p.y;
                p = __builtin_amdgcn_cvt_pk_f32_fp8(d1, true);  acc[6]  += p.x; acc[7]  += p.y;
                p = __builtin_amdgcn_cvt_pk_f32_fp8(d2, false); acc[8]  += p.x; acc[9]  += p.y;
                p = __builtin_amdgcn_cvt_pk_f32_fp8(d2, true);  acc[10] += p.x; acc[11] += p.y;
                p = __builtin_amdgcn_cvt_pk_f32_fp8(d3, false); acc[12] += p.x; acc[13] += p.y;
                p = __builtin_amdgcn_cvt_pk_f32_fp8(d3, true);  acc[14] += p.x; acc[15] += p.y;
                p = __builtin_amdgcn_cvt_pk_f32_fp8(d4, false); acc[16] += p.x; acc[17] += p.y;
                p = __builtin_amdgcn_cvt_pk_f32_fp8(d4, true);  acc[18] += p.x; acc[19] += p.y;
                p = __builtin_amdgcn_cvt_pk_f32_fp8(d5, false); acc[20] += p.x;
            }
        }
    }

    // ---- logits = h[i,:] + pair/64 ; log-softmax ; pick gold = X[m,i]
    const float* hrow = h + i * Q_SYM;
    const float INV = 1.0f / 64.0f;
    float logits[Q_SYM];
    #pragma unroll
    for (int a = 0; a < Q_SYM; ++a) logits[a] = hrow[a] + acc[a] * INV;

    float mx = -3.4e38f;
    #pragma unroll
    for (int a = 0; a < Q_SYM; ++a) mx = fmaxf(mx, logits[a]);
    float s = 0.0f;
    #pragma unroll
    for (int a = 0; a < Q_SYM; ++a) s += __expf(logits[a] - mx);
    int g = xrow[i];
    float gold = 0.0f;
    #pragma unroll
    for (int a = 0; a < Q_SYM; ++a) gold = (a == g) ? logits[a] : gold;
    float logp = gold - mx - __logf(s);
    float v = -W[m] * logp;

    // ---- fold regularization (blockIdx.x==0 blocks; each lower-tri (i,j,a,b) once)
    if (do_reg) {
        v += 1e-4f * regsum;
        if (tid < Q_SYM) {
            float hv = hrow[tid];
            v += 1e-6f * hv * hv;
        }
    }

    __syncthreads();   // LDS reuse safety before reduction
    float tot = wave_block_reduce(v, red, tid);
    if (tid == 0) atomicAdd(out, tot);
}

extern "C" void kernel_launch(void* const* d_in, const int* in_sizes, int n_in,
                              void* d_out, int out_size, void* d_ws, size_t ws_size,
                              hipStream_t stream) {
    const int*   X = (const int*)d_in[0];
    const float* W = (const float*)d_in[1];
    const float* h = (const float*)d_in[2];
    const float* J = (const float*)d_in[3];
    float* out = (float*)d_out;

    hipLaunchKernelGGL(zero_out, dim3(1), dim3(1), 0, stream, out);
    dim3 grid(M_SEQ / 256, L_POS);
    hipLaunchKernelGGL(pair_nll_kernel, grid, dim3(256), 0, stream, X, W, h, J, out);
}

// Round 6
// 528.861 us; speedup vs baseline: 1.0116x; 1.0116x over previous
//
#include <hip/hip_runtime.h>

// ArDCA loss: loss = -sum_{m,i} W[m] * log_softmax(h[i,:] + sum_{j<i} J[i,j,:,X[m,j]])[X[m,i]]
//             + 1e-6 * sum h^2 + 1e-4 * sum_{j<i} J^2
// M=8192, L=256, Q=21. Output: single fp32 scalar.
//
// R6: bf8(e5m2) LDS tiles + free unpack. e5m2 is exactly the top byte of an
// f16 (same bias, subnormals map) so unpack = v_perm_b32 (full-rate) and
// accumulate = v_pk_add_f16 (full-rate). R5's lesson: v_cvt_pk_f32_fp8 is
// quarter-rate (~8cyc) -> 232us VALU wall; this replaces 32 slow+full-rate
// ops/item with ~22 full-rate ops/item (~85us), back under the ~145us LDS
// path. LDS layout unchanged from R5 (JA float4 16B + JB float2 8B per row;
// conflicts measured 1.4e7 = near-floor).
// Scale J by 64 at pack (sigma 0.01 -> 0.64), unscale 1/64 in epilogue.
// Reg terms folded into blockIdx.x==0 staging on exact fp32 values (R4).
// dur_us carries ~110us harness constant on top of the pair dispatch.

#define M_SEQ 8192
#define L_POS 256
#define Q_SYM 21
#define QQ    441
#define JC    16
#define NROWS (JC * Q_SYM)       // 336 rows per chunk

typedef _Float16 half2v __attribute__((ext_vector_type(2)));

__device__ __forceinline__ half2v h2_from_u32(unsigned u) {
    union { unsigned u; half2v h; } c; c.u = u; return c.h;
}

// pack 4 floats to 4 e5m2 bytes
__device__ __forceinline__ unsigned pack4_bf8(float a, float b, float c, float d) {
    int w = __builtin_amdgcn_cvt_pk_bf8_f32(a, b, 0, false);   // bytes 0,1
    w = __builtin_amdgcn_cvt_pk_bf8_f32(c, d, w, true);        // bytes 2,3
    return (unsigned)w;
}

// dword of 4 e5m2 bytes -> two half2 (lo = bytes 0,1 ; hi = bytes 2,3)
// f16 = e5m2_byte << 8  (exact: same exponent bias, subnormals map)
__device__ __forceinline__ half2v bf8lo_h2(unsigned d) {
    return h2_from_u32(__builtin_amdgcn_perm(0u, d, 0x010C000Cu)); // [0,b0,0,b1]
}
__device__ __forceinline__ half2v bf8hi_h2(unsigned d) {
    return h2_from_u32(__builtin_amdgcn_perm(0u, d, 0x030C020Cu)); // [0,b2,0,b3]
}

__device__ __forceinline__ float wave_block_reduce(float v, float* red, int tid) {
    #pragma unroll
    for (int off = 32; off > 0; off >>= 1) v += __shfl_down(v, off, 64);
    if ((tid & 63) == 0) red[tid >> 6] = v;
    __syncthreads();
    return red[0] + red[1] + red[2] + red[3];
}

__global__ void zero_out(float* __restrict__ out) { out[0] = 0.0f; }

// One block per (m-chunk of 256, i). Each thread owns one m.
__global__ __launch_bounds__(256) void pair_nll_kernel(const int* __restrict__ X,
                                                       const float* __restrict__ W,
                                                       const float* __restrict__ h,
                                                       const float* __restrict__ J,
                                                       float* __restrict__ out) {
    __shared__ float4 JA[NROWS];     // 16 bf8 per row (values 0..15)  5376 B
    __shared__ float2 JB[NROWS];     // 5 bf8 + pad    (values 16..20) 2688 B
    __shared__ float red[4];

    const int tid = threadIdx.x;
    const int i  = blockIdx.y;
    const int m  = blockIdx.x * 256 + tid;
    const bool do_reg = (blockIdx.x == 0);
    const int* xrow = X + (size_t)m * L_POS;

    // thread-owned staging rows (fixed for whole kernel)
    const int row0 = tid;                       // 0..255
    const int jc0  = row0 / Q_SYM;
    const int b0   = row0 - jc0 * Q_SYM;
    const int row1 = tid + 256;                 // 256..335 valid when tid < 80
    const int jc1  = row1 / Q_SYM;
    const int b1   = row1 - jc1 * Q_SYM;
    const bool has_row1 = (row1 < NROWS);

    half2v acc[11];   // 10 pairs + acc[10].x for value 20
    #pragma unroll
    for (int k = 0; k < 11; ++k) { acc[k].x = (_Float16)0.f; acc[k].y = (_Float16)0.f; }
    float regsum = 0.0f;
    const float SC = 64.0f;

    for (int j0 = 0; j0 < i; j0 += JC) {
        const float* Jsrc = J + ((size_t)i * L_POS + j0) * QQ;
        __syncthreads();   // protect previous chunk's LDS reads

        // ---- stage: each thread converts+packs its row(s)
        {
            const float* s = Jsrc + jc0 * QQ + b0;
            float v[Q_SYM];
            #pragma unroll
            for (int a = 0; a < Q_SYM; ++a) v[a] = s[a * Q_SYM];
            if (do_reg && (j0 + jc0 < i)) {
                float rs = 0.0f;
                #pragma unroll
                for (int a = 0; a < Q_SYM; ++a) rs += v[a] * v[a];
                regsum += rs;
            }
            unsigned w0 = pack4_bf8(SC*v[0],  SC*v[1],  SC*v[2],  SC*v[3]);
            unsigned w1 = pack4_bf8(SC*v[4],  SC*v[5],  SC*v[6],  SC*v[7]);
            unsigned w2 = pack4_bf8(SC*v[8],  SC*v[9],  SC*v[10], SC*v[11]);
            unsigned w3 = pack4_bf8(SC*v[12], SC*v[13], SC*v[14], SC*v[15]);
            unsigned w4 = pack4_bf8(SC*v[16], SC*v[17], SC*v[18], SC*v[19]);
            unsigned w5 = (unsigned)__builtin_amdgcn_cvt_pk_bf8_f32(SC*v[20], 0.f, 0, false);
            JA[row0] = make_float4(__builtin_bit_cast(float, w0),
                                   __builtin_bit_cast(float, w1),
                                   __builtin_bit_cast(float, w2),
                                   __builtin_bit_cast(float, w3));
            JB[row0] = make_float2(__builtin_bit_cast(float, w4),
                                   __builtin_bit_cast(float, w5));
        }
        if (has_row1) {
            const float* s = Jsrc + jc1 * QQ + b1;
            float v[Q_SYM];
            #pragma unroll
            for (int a = 0; a < Q_SYM; ++a) v[a] = s[a * Q_SYM];
            if (do_reg && (j0 + jc1 < i)) {
                float rs = 0.0f;
                #pragma unroll
                for (int a = 0; a < Q_SYM; ++a) rs += v[a] * v[a];
                regsum += rs;
            }
            unsigned w0 = pack4_bf8(SC*v[0],  SC*v[1],  SC*v[2],  SC*v[3]);
            unsigned w1 = pack4_bf8(SC*v[4],  SC*v[5],  SC*v[6],  SC*v[7]);
            unsigned w2 = pack4_bf8(SC*v[8],  SC*v[9],  SC*v[10], SC*v[11]);
            unsigned w3 = pack4_bf8(SC*v[12], SC*v[13], SC*v[14], SC*v[15]);
            unsigned w4 = pack4_bf8(SC*v[16], SC*v[17], SC*v[18], SC*v[19]);
            unsigned w5 = (unsigned)__builtin_amdgcn_cvt_pk_bf8_f32(SC*v[20], 0.f, 0, false);
            JA[row1] = make_float4(__builtin_bit_cast(float, w0),
                                   __builtin_bit_cast(float, w1),
                                   __builtin_bit_cast(float, w2),
                                   __builtin_bit_cast(float, w3));
            JB[row1] = make_float2(__builtin_bit_cast(float, w4),
                                   __builtin_bit_cast(float, w5));
        }
        __syncthreads();

        // ---- this thread's 16 X values (row-contiguous, vectorized)
        int4 xa = *(const int4*)(xrow + j0);
        int4 xb = *(const int4*)(xrow + j0 + 4);
        int4 xc = *(const int4*)(xrow + j0 + 8);
        int4 xd = *(const int4*)(xrow + j0 + 12);
        int xv[JC] = {xa.x, xa.y, xa.z, xa.w, xb.x, xb.y, xb.z, xb.w,
                      xc.x, xc.y, xc.z, xc.w, xd.x, xd.y, xd.z, xd.w};

        #pragma unroll
        for (int jc = 0; jc < JC; ++jc) {
            if (j0 + jc < i) {   // block-uniform guard (scalar branch)
                int r = jc * Q_SYM + xv[jc];
                float4 lo = JA[r];
                float2 hi = JB[r];
                unsigned d0 = __builtin_bit_cast(unsigned, lo.x);
                unsigned d1 = __builtin_bit_cast(unsigned, lo.y);
                unsigned d2 = __builtin_bit_cast(unsigned, lo.z);
                unsigned d3 = __builtin_bit_cast(unsigned, lo.w);
                unsigned d4 = __builtin_bit_cast(unsigned, hi.x);
                unsigned d5 = __builtin_bit_cast(unsigned, hi.y);
                acc[0]  += bf8lo_h2(d0);  acc[1]  += bf8hi_h2(d0);
                acc[2]  += bf8lo_h2(d1);  acc[3]  += bf8hi_h2(d1);
                acc[4]  += bf8lo_h2(d2);  acc[5]  += bf8hi_h2(d2);
                acc[6]  += bf8lo_h2(d3);  acc[7]  += bf8hi_h2(d3);
                acc[8]  += bf8lo_h2(d4);  acc[9]  += bf8hi_h2(d4);
                acc[10] += bf8lo_h2(d5);                       // (v20, 0)
            }
        }
    }

    // ---- logits = h[i,:] + pair/64 ; log-softmax ; pick gold = X[m,i]
    const float* hrow = h + i * Q_SYM;
    const float INV = 1.0f / 64.0f;
    float logits[Q_SYM];
    #pragma unroll
    for (int k = 0; k < 10; ++k) {
        logits[2 * k]     = hrow[2 * k]     + (float)acc[k].x * INV;
        logits[2 * k + 1] = hrow[2 * k + 1] + (float)acc[k].y * INV;
    }
    logits[20] = hrow[20] + (float)acc[10].x * INV;

    float mx = -3.4e38f;
    #pragma unroll
    for (int a = 0; a < Q_SYM; ++a) mx = fmaxf(mx, logits[a]);
    float s = 0.0f;
    #pragma unroll
    for (int a = 0; a < Q_SYM; ++a) s += __expf(logits[a] - mx);
    int g = xrow[i];
    float gold = 0.0f;
    #pragma unroll
    for (int a = 0; a < Q_SYM; ++a) gold = (a == g) ? logits[a] : gold;
    float logp = gold - mx - __logf(s);
    float v = -W[m] * logp;

    // ---- fold regularization (blockIdx.x==0 blocks; each lower-tri (i,j,a,b) once)
    if (do_reg) {
        v += 1e-4f * regsum;
        if (tid < Q_SYM) {
            float hv = hrow[tid];
            v += 1e-6f * hv * hv;
        }
    }

    __syncthreads();   // LDS reuse safety before reduction
    float tot = wave_block_reduce(v, red, tid);
    if (tid == 0) atomicAdd(out, tot);
}

extern "C" void kernel_launch(void* const* d_in, const int* in_sizes, int n_in,
                              void* d_out, int out_size, void* d_ws, size_t ws_size,
                              hipStream_t stream) {
    const int*   X = (const int*)d_in[0];
    const float* W = (const float*)d_in[1];
    const float* h = (const float*)d_in[2];
    const float* J = (const float*)d_in[3];
    float* out = (float*)d_out;

    hipLaunchKernelGGL(zero_out, dim3(1), dim3(1), 0, stream, out);
    dim3 grid(M_SEQ / 256, L_POS);
    hipLaunchKernelGGL(pair_nll_kernel, grid, dim3(256), 0, stream, X, W, h, J, out);
}